// Round 2
// baseline (796.035 us; speedup 1.0000x reference)
//
#include <hip/hip_runtime.h>
#include <hip/hip_bf16.h>
#include <math.h>

// EncoderLayer_68186900791439 — graph transformer encoder layer on MI355X.
// Round 2: inputs/outputs are FLOAT32 (per reference dtypes; round-1 NaN came
// from misreading f32 buffers as bf16). Intermediates y/q/k/v/h/h1 stored bf16
// (ws footprint ~120 MB, faster gathers); accumulation and residuals f32.
// Pipeline: LN1 -> {q,k,v,skip} GEMMs -> CSR-by-dst -> wave-per-node online
// softmax attention (+head mean +skip +residual, in-place) -> LN2 -> GELU FFN.

typedef unsigned short u16;

__device__ __forceinline__ float bf2f(u16 u) {
    return __uint_as_float(((unsigned int)u) << 16);
}
__device__ __forceinline__ u16 f2bf(float f) {
    __hip_bfloat16 h = __float2bfloat16(f);
    return __builtin_bit_cast(u16, h);
}

// ---------------- LayerNorm: one wave (64 lanes) per row of 128; f32 in, bf16 out
__global__ __launch_bounds__(256) void ln_kernel(
    const float* __restrict__ x, const float* __restrict__ g,
    const float* __restrict__ b, u16* __restrict__ y, int n)
{
    int wid = threadIdx.x >> 6, lane = threadIdx.x & 63;
    int row = blockIdx.x * 4 + wid;
    if (row >= n) return;
    size_t base = (size_t)row * 128;
    float v0 = x[base + lane];
    float v1 = x[base + 64 + lane];
    float s1 = v0 + v1, s2 = v0 * v0 + v1 * v1;
    for (int o = 1; o <= 32; o <<= 1) {
        s1 += __shfl_xor(s1, o);
        s2 += __shfl_xor(s2, o);
    }
    float mu = s1 * (1.f / 128.f);
    float var = s2 * (1.f / 128.f) - mu * mu;
    float rstd = rsqrtf(var + 1e-5f);
    y[base + lane]      = f2bf((v0 - mu) * rstd * g[lane] + b[lane]);
    y[base + 64 + lane] = f2bf((v1 - mu) * rstd * g[64 + lane] + b[64 + lane]);
}

// ---------------- GEMM: A[n x 128] bf16 @ B[128 x M] f32 + bias(f32) ----------
// MODE 0: f32 out.  MODE 1: bf16 out.  MODE 2: exact GELU -> bf16 out.
// MODE 3: resid(f32) + val -> f32 out.
// Block: 256 thr, tile 32 rows x 128 cols, 4x4 register micro-tiles. LDS 50KB.
template <int MODE>
__global__ __launch_bounds__(256) void gemm128(
    const u16* __restrict__ A, const float* __restrict__ B,
    const float* __restrict__ bias, void* __restrict__ out,
    const float* __restrict__ resid, int n, int M)
{
    __shared__ float As[128][36];     // transposed A tile: As[d][r]; 36 keeps float4 align
    __shared__ u16 Bs[128 * 128];     // B tile converted to bf16
    int tid = threadIdx.x;
    int r0 = blockIdx.x * 32;
    int c0 = blockIdx.y * 128;

    for (int i = tid; i < 32 * 128; i += 256) {
        int r = i >> 7, d = i & 127;
        float va = 0.f;
        if (r0 + r < n) va = bf2f(A[(size_t)(r0 + r) * 128 + d]);
        As[d][r] = va;
    }
    for (int i = tid; i < 128 * 128; i += 256) {
        int d = i >> 7, c = i & 127;
        Bs[i] = f2bf(B[(size_t)d * M + c0 + c]);
    }
    __syncthreads();

    int tx = tid & 31, ty = tid >> 5;
    float acc[4][4] = {};
#pragma unroll 4
    for (int d = 0; d < 128; ++d) {
        float4 av = *(const float4*)&As[d][ty * 4];
        ushort4 bu = *(const ushort4*)&Bs[d * 128 + tx * 4];
        float b0 = bf2f(bu.x), b1 = bf2f(bu.y), b2 = bf2f(bu.z), b3 = bf2f(bu.w);
        acc[0][0] += av.x * b0; acc[0][1] += av.x * b1; acc[0][2] += av.x * b2; acc[0][3] += av.x * b3;
        acc[1][0] += av.y * b0; acc[1][1] += av.y * b1; acc[1][2] += av.y * b2; acc[1][3] += av.y * b3;
        acc[2][0] += av.z * b0; acc[2][1] += av.z * b1; acc[2][2] += av.z * b2; acc[2][3] += av.z * b3;
        acc[3][0] += av.w * b0; acc[3][1] += av.w * b1; acc[3][2] += av.w * b2; acc[3][3] += av.w * b3;
    }

    float4 bb = *(const float4*)(bias + c0 + tx * 4);
#pragma unroll
    for (int ii = 0; ii < 4; ++ii) {
        int row = r0 + ty * 4 + ii;
        if (row >= n) continue;
        float v0 = acc[ii][0] + bb.x, v1 = acc[ii][1] + bb.y;
        float v2 = acc[ii][2] + bb.z, v3 = acc[ii][3] + bb.w;
        size_t ob = (size_t)row * M + c0 + tx * 4;
        if (MODE == 0) {
            *(float4*)((float*)out + ob) = make_float4(v0, v1, v2, v3);
        } else if (MODE == 1) {
            ushort4 o4 = { f2bf(v0), f2bf(v1), f2bf(v2), f2bf(v3) };
            *(ushort4*)((u16*)out + ob) = o4;
        } else if (MODE == 2) {
            v0 = 0.5f * v0 * (1.f + erff(v0 * 0.70710678118654752f));
            v1 = 0.5f * v1 * (1.f + erff(v1 * 0.70710678118654752f));
            v2 = 0.5f * v2 * (1.f + erff(v2 * 0.70710678118654752f));
            v3 = 0.5f * v3 * (1.f + erff(v3 * 0.70710678118654752f));
            ushort4 o4 = { f2bf(v0), f2bf(v1), f2bf(v2), f2bf(v3) };
            *(ushort4*)((u16*)out + ob) = o4;
        } else {
            float4 rs = *(const float4*)(resid + ob);
            *(float4*)((float*)out + ob) =
                make_float4(v0 + rs.x, v1 + rs.y, v2 + rs.z, v3 + rs.w);
        }
    }
}

// ---------------- CSR build (group edges by dst) ----------------
__global__ __launch_bounds__(256) void zero_kernel(int* __restrict__ p, int n) {
    int i = blockIdx.x * 256 + threadIdx.x;
    if (i < n) p[i] = 0;
}
__global__ __launch_bounds__(256) void hist_kernel(const int* __restrict__ dst,
                                                   int* __restrict__ cnt, int e) {
    int stride = gridDim.x * blockDim.x;
    for (int i = blockIdx.x * blockDim.x + threadIdx.x; i < e; i += stride)
        atomicAdd(&cnt[dst[i]], 1);
}
__global__ __launch_bounds__(256) void scan_block_sum(const int* __restrict__ cnt,
                                                      int* __restrict__ bsum, int n) {
    __shared__ int s[256];
    int idx = blockIdx.x * 256 + threadIdx.x;
    s[threadIdx.x] = (idx < n) ? cnt[idx] : 0;
    __syncthreads();
    for (int o = 128; o > 0; o >>= 1) {
        if (threadIdx.x < o) s[threadIdx.x] += s[threadIdx.x + o];
        __syncthreads();
    }
    if (threadIdx.x == 0) bsum[blockIdx.x] = s[0];
}
__global__ __launch_bounds__(256) void scan_partials(const int* __restrict__ bsum,
                                                     int* __restrict__ bsumex, int nb) {
    __shared__ int s[256];
    int t = threadIdx.x;
    int v = (t < nb) ? bsum[t] : 0;
    s[t] = v;
    __syncthreads();
    for (int o = 1; o < 256; o <<= 1) {
        int add = (t >= o) ? s[t - o] : 0;
        __syncthreads();
        s[t] += add;
        __syncthreads();
    }
    bsumex[t] = s[t] - v;
}
__global__ __launch_bounds__(256) void scan_write(const int* __restrict__ cnt,
                                                  const int* __restrict__ bsumex,
                                                  int* __restrict__ rowptr,
                                                  int* __restrict__ cursor, int n, int etot) {
    __shared__ int s[256];
    int t = threadIdx.x;
    int idx = blockIdx.x * 256 + t;
    int v = (idx < n) ? cnt[idx] : 0;
    s[t] = v;
    __syncthreads();
    for (int o = 1; o < 256; o <<= 1) {
        int add = (t >= o) ? s[t - o] : 0;
        __syncthreads();
        s[t] += add;
        __syncthreads();
    }
    if (idx < n) {
        int ex = bsumex[blockIdx.x] + s[t] - v;
        rowptr[idx] = ex;
        cursor[idx] = ex;
    }
    if (idx == 0) rowptr[n] = etot;
}
__global__ __launch_bounds__(256) void scatter_kernel(const int* __restrict__ dst,
                                                      int* __restrict__ cursor,
                                                      int* __restrict__ eids, int e) {
    int stride = gridDim.x * blockDim.x;
    for (int i = blockIdx.x * blockDim.x + threadIdx.x; i < e; i += stride) {
        int p = atomicAdd(&cursor[dst[i]], 1);
        eids[p] = i;
    }
}

// ---------------- Attention: one wave per dst node, online softmax ----------------
// Lane l holds flattened qkv columns [4l, 4l+4): lanes 0-31 head 0, 32-63 head 1.
// Fuses head-mean + skip + residual; writes x2 in-place over `sx` (skip buffer).
__global__ __launch_bounds__(256) void attn_kernel(
    const u16* __restrict__ q, const u16* __restrict__ k,
    const u16* __restrict__ v, const int* __restrict__ rowptr,
    const int* __restrict__ eids, const int* __restrict__ src,
    const float* __restrict__ x, float* __restrict__ sx, int n)
{
    int wid = threadIdx.x >> 6, lane = threadIdx.x & 63;
    int i = blockIdx.x * 4 + wid;
    if (i >= n) return;
    ushort4 qu = *(const ushort4*)(q + (size_t)i * 256 + lane * 4);
    float q0 = bf2f(qu.x), q1 = bf2f(qu.y), q2 = bf2f(qu.z), q3 = bf2f(qu.w);
    int beg = rowptr[i], end = rowptr[i + 1];
    float m = -INFINITY, l = 0.f;
    float a0 = 0.f, a1 = 0.f, a2 = 0.f, a3 = 0.f;
    for (int t = beg; t < end; ++t) {
        int e = eids[t];
        int s = src[e];
        ushort4 ku = *(const ushort4*)(k + (size_t)s * 256 + lane * 4);
        float part = q0 * bf2f(ku.x) + q1 * bf2f(ku.y) + q2 * bf2f(ku.z) + q3 * bf2f(ku.w);
        part += __shfl_xor(part, 1);
        part += __shfl_xor(part, 2);
        part += __shfl_xor(part, 4);
        part += __shfl_xor(part, 8);
        part += __shfl_xor(part, 16);          // reduce over the 32-lane head group
        float alpha = part * 0.08838834764831845f;  // 1/sqrt(128)
        float nm = fmaxf(m, alpha);
        float sc = expf(m - nm);               // m=-inf first iter -> 0
        float p = expf(alpha - nm);
        l = l * sc + p;
        ushort4 vu = *(const ushort4*)(v + (size_t)s * 256 + lane * 4);
        a0 = a0 * sc + p * bf2f(vu.x);
        a1 = a1 * sc + p * bf2f(vu.y);
        a2 = a2 * sc + p * bf2f(vu.z);
        a3 = a3 * sc + p * bf2f(vu.w);
        m = nm;
    }
    float inv = (l > 0.f) ? (1.f / l) : 0.f;   // empty segment -> attn = 0
    a0 *= inv; a1 *= inv; a2 *= inv; a3 *= inv;
    float o0 = 0.5f * (a0 + __shfl_xor(a0, 32));  // mean over the 2 heads
    float o1 = 0.5f * (a1 + __shfl_xor(a1, 32));
    float o2 = 0.5f * (a2 + __shfl_xor(a2, 32));
    float o3 = 0.5f * (a3 + __shfl_xor(a3, 32));
    if (lane < 32) {
        size_t base = (size_t)i * 128 + lane * 4;
        float4 xv = *(const float4*)(x + base);
        float4 sk = *(const float4*)(sx + base);
        float4 r;
        r.x = xv.x + sk.x + o0;
        r.y = xv.y + sk.y + o1;
        r.z = xv.z + sk.z + o2;
        r.w = xv.w + sk.w + o3;
        *(float4*)(sx + base) = r;   // x2 in-place (read-before-write, same thread)
    }
}

extern "C" void kernel_launch(void* const* d_in, const int* in_sizes, int n_in,
                              void* d_out, int out_size, void* d_ws, size_t ws_size,
                              hipStream_t stream)
{
    const float* x    = (const float*)d_in[0];
    const int*   ei   = (const int*)d_in[1];
    const float* ln1g = (const float*)d_in[2];
    const float* ln1b = (const float*)d_in[3];
    const float* Wq   = (const float*)d_in[4];
    const float* bq   = (const float*)d_in[5];
    const float* Wk   = (const float*)d_in[6];
    const float* bk   = (const float*)d_in[7];
    const float* Wv   = (const float*)d_in[8];
    const float* bv   = (const float*)d_in[9];
    const float* Wsk  = (const float*)d_in[10];
    const float* bsk  = (const float*)d_in[11];
    const float* ln2g = (const float*)d_in[12];
    const float* ln2b = (const float*)d_in[13];
    const float* W1   = (const float*)d_in[14];
    const float* b1   = (const float*)d_in[15];
    const float* W2   = (const float*)d_in[16];
    const float* b2   = (const float*)d_in[17];

    int n = in_sizes[0] / 128;     // 50000
    int e = in_sizes[1] / 2;       // 800000
    const int* src  = ei;          // edge_index[0] (messages src -> dst)
    const int* dstp = ei + e;      // edge_index[1]

    char* w = (char*)d_ws;
    size_t off = 0;
    auto alloc = [&](size_t bytes) -> void* {
        void* p = w + off;
        off = (off + bytes + 255) & ~(size_t)255;
        return p;
    };
    u16*   y    = (u16*)alloc((size_t)n * 128 * 2);   // LN1 out; reused as h (LN2 out)
    u16*   qb   = (u16*)alloc((size_t)n * 256 * 2);   // q; reused as h1 (GELU out, n*128)
    u16*   kb   = (u16*)alloc((size_t)n * 256 * 2);
    u16*   vb   = (u16*)alloc((size_t)n * 256 * 2);
    float* sx   = (float*)alloc((size_t)n * 128 * 4); // skip, then x2 in-place
    int* cnt    = (int*)alloc((size_t)n * 4);
    int* cursor = (int*)alloc((size_t)n * 4);
    int* rowptr = (int*)alloc(((size_t)n + 1) * 4);
    int* eids   = (int*)alloc((size_t)e * 4);
    int* bsum   = (int*)alloc(1024);
    int* bsumex = (int*)alloc(1024);

    int lnGrid = (n + 3) / 4;
    int gx = (n + 31) / 32;
    int nb = (n + 255) / 256;

    // LN1
    ln_kernel<<<lnGrid, 256, 0, stream>>>(x, ln1g, ln1b, y, n);
    // projections
    gemm128<1><<<dim3(gx, 2), 256, 0, stream>>>(y, Wq, bq, qb, nullptr, n, 256);
    gemm128<1><<<dim3(gx, 2), 256, 0, stream>>>(y, Wk, bk, kb, nullptr, n, 256);
    gemm128<1><<<dim3(gx, 2), 256, 0, stream>>>(y, Wv, bv, vb, nullptr, n, 256);
    gemm128<0><<<dim3(gx, 1), 256, 0, stream>>>(y, Wsk, bsk, sx, nullptr, n, 128);
    // CSR by dst
    zero_kernel<<<nb, 256, 0, stream>>>(cnt, n);
    hist_kernel<<<1024, 256, 0, stream>>>(dstp, cnt, e);
    scan_block_sum<<<nb, 256, 0, stream>>>(cnt, bsum, n);
    scan_partials<<<1, 256, 0, stream>>>(bsum, bsumex, nb);
    scan_write<<<nb, 256, 0, stream>>>(cnt, bsumex, rowptr, cursor, n, e);
    scatter_kernel<<<1024, 256, 0, stream>>>(dstp, cursor, eids, e);
    // attention + head-mean + skip + residual -> sx (in place)
    attn_kernel<<<(n + 3) / 4, 256, 0, stream>>>(qb, kb, vb, rowptr, eids, src,
                                                 x, sx, n);
    // FFN (h into y buffer, h1 into q buffer)
    ln_kernel<<<lnGrid, 256, 0, stream>>>(sx, ln2g, ln2b, y, n);
    gemm128<2><<<dim3(gx, 1), 256, 0, stream>>>(y, W1, b1, qb, nullptr, n, 128);
    gemm128<3><<<dim3(gx, 1), 256, 0, stream>>>(qb, W2, b2, d_out, sx, n, 128);
}

// Round 3
// 520.600 us; speedup vs baseline: 1.5291x; 1.5291x over previous
//
#include <hip/hip_runtime.h>
#include <hip/hip_bf16.h>
#include <math.h>

// EncoderLayer_68186900791439 — graph transformer encoder layer on MI355X.
// Round 3: MFMA GEMMs. Weights pre-transposed+converted to bf16 W^T[M][128]
// once per call; A (bf16 activations) and B fragments are then contiguous 16B
// global loads (no LDS, no barrier). Attention: 2-edge unrolled online softmax.

typedef unsigned short u16;
using short8 = __attribute__((ext_vector_type(8))) short;   // 8 bf16 = 4 VGPRs
using f32x4  = __attribute__((ext_vector_type(4))) float;   // 4 f32 acc

__device__ __forceinline__ float bf2f(u16 u) {
    return __uint_as_float(((unsigned int)u) << 16);
}
__device__ __forceinline__ u16 f2bf(float f) {
    __hip_bfloat16 h = __float2bfloat16(f);
    return __builtin_bit_cast(u16, h);
}

// ---------------- LayerNorm: one wave per row of 128; f32 in, bf16 out -------
__global__ __launch_bounds__(256) void ln_kernel(
    const float* __restrict__ x, const float* __restrict__ g,
    const float* __restrict__ b, u16* __restrict__ y, int n)
{
    int wid = threadIdx.x >> 6, lane = threadIdx.x & 63;
    int row = blockIdx.x * 4 + wid;
    if (row >= n) return;
    size_t base = (size_t)row * 128;
    float v0 = x[base + lane];
    float v1 = x[base + 64 + lane];
    float s1 = v0 + v1, s2 = v0 * v0 + v1 * v1;
    for (int o = 1; o <= 32; o <<= 1) {
        s1 += __shfl_xor(s1, o);
        s2 += __shfl_xor(s2, o);
    }
    float mu = s1 * (1.f / 128.f);
    float var = s2 * (1.f / 128.f) - mu * mu;
    float rstd = rsqrtf(var + 1e-5f);
    y[base + lane]      = f2bf((v0 - mu) * rstd * g[lane] + b[lane]);
    y[base + 64 + lane] = f2bf((v1 - mu) * rstd * g[64 + lane] + b[64 + lane]);
}

// ------------- Weight prep: W[128 x N] f32 -> Wt[N x 128] bf16, 6 segments ----
__global__ __launch_bounds__(256) void prep_weights(
    const float* __restrict__ Wq, const float* __restrict__ Wk,
    const float* __restrict__ Wv, const float* __restrict__ Ws,
    const float* __restrict__ W1, const float* __restrict__ W2,
    u16* __restrict__ out)
{
    int i = blockIdx.x * 256 + threadIdx.x;          // 0 .. 147455
    if (i >= 147456) return;
    const float* W; int N; int base;
    if      (i <  32768) { W = Wq; N = 256; base = 0; }
    else if (i <  65536) { W = Wk; N = 256; base = 32768; }
    else if (i <  98304) { W = Wv; N = 256; base = 65536; }
    else if (i < 114688) { W = Ws; N = 128; base = 98304; }
    else if (i < 131072) { W = W1; N = 128; base = 114688; }
    else                 { W = W2; N = 128; base = 131072; }
    int j = i - base;
    int nIdx = j >> 7, k = j & 127;
    out[i] = f2bf(W[(size_t)k * N + nIdx]);
}

// ------------- MFMA GEMM: C[n x M] = A[n x 128] @ Bt^T + bias ----------------
// A bf16 row-major, Bt = B^T bf16 [M x 128] row-major. Wave: 32x32 (2x2 accs
// of 16x16x32), block 2x2 waves = 64x64 tile. A/B frags: contiguous 16B loads.
// MODE 0: f32 out. MODE 1: bf16 out. MODE 2: exact GELU -> bf16 out.
// MODE 3: resid(f32) + val -> f32 out.
template <int MODE>
__global__ __launch_bounds__(256) void mfma_gemm(
    const u16* __restrict__ A, const u16* __restrict__ Bt,
    const float* __restrict__ bias, void* __restrict__ out,
    const float* __restrict__ resid, int n, int M)
{
    int wid = threadIdx.x >> 6, lane = threadIdx.x & 63;
    int wr = wid >> 1, wc = wid & 1;
    int r0 = blockIdx.x * 64 + wr * 32;
    int c0 = blockIdx.y * 64 + wc * 32;
    int lm = lane & 15, quad = lane >> 4;

    // A rows r0+lm / r0+16+lm may overrun n for the last block: reads land in
    // the adjacent ws buffer (contiguous allocs) — garbage only feeds rows we
    // never store. Stores are guarded by row < n.
    const u16* aBase = A  + (size_t)(r0 + lm) * 128 + quad * 8;
    const u16* bBase = Bt + (size_t)(c0 + lm) * 128 + quad * 8;

    f32x4 acc[2][2] = {};
#pragma unroll
    for (int kk = 0; kk < 128; kk += 32) {
        short8 a0 = *(const short8*)(aBase + kk);
        short8 a1 = *(const short8*)(aBase + 16 * 128 + kk);
        short8 b0 = *(const short8*)(bBase + kk);
        short8 b1 = *(const short8*)(bBase + 16 * 128 + kk);
        acc[0][0] = __builtin_amdgcn_mfma_f32_16x16x32_bf16(a0, b0, acc[0][0], 0, 0, 0);
        acc[0][1] = __builtin_amdgcn_mfma_f32_16x16x32_bf16(a0, b1, acc[0][1], 0, 0, 0);
        acc[1][0] = __builtin_amdgcn_mfma_f32_16x16x32_bf16(a1, b0, acc[1][0], 0, 0, 0);
        acc[1][1] = __builtin_amdgcn_mfma_f32_16x16x32_bf16(a1, b1, acc[1][1], 0, 0, 0);
    }

#pragma unroll
    for (int ct = 0; ct < 2; ++ct) {
        int col = c0 + ct * 16 + lm;
        float bv = bias[col];
#pragma unroll
        for (int rt = 0; rt < 2; ++rt) {
#pragma unroll
            for (int i2 = 0; i2 < 4; ++i2) {
                int row = r0 + rt * 16 + quad * 4 + i2;
                if (row >= n) continue;
                float v = acc[rt][ct][i2] + bv;
                size_t ob = (size_t)row * M + col;
                if (MODE == 0) {
                    ((float*)out)[ob] = v;
                } else if (MODE == 1) {
                    ((u16*)out)[ob] = f2bf(v);
                } else if (MODE == 2) {
                    v = 0.5f * v * (1.f + erff(v * 0.70710678118654752f));
                    ((u16*)out)[ob] = f2bf(v);
                } else {
                    ((float*)out)[ob] = v + resid[ob];
                }
            }
        }
    }
}

// ---------------- CSR build (group edges by dst) ----------------
__global__ __launch_bounds__(256) void zero_kernel(int* __restrict__ p, int n) {
    int i = blockIdx.x * 256 + threadIdx.x;
    if (i < n) p[i] = 0;
}
__global__ __launch_bounds__(256) void hist_kernel(const int* __restrict__ dst,
                                                   int* __restrict__ cnt, int e) {
    int stride = gridDim.x * blockDim.x;
    for (int i = blockIdx.x * blockDim.x + threadIdx.x; i < e; i += stride)
        atomicAdd(&cnt[dst[i]], 1);
}
__global__ __launch_bounds__(256) void scan_block_sum(const int* __restrict__ cnt,
                                                      int* __restrict__ bsum, int n) {
    __shared__ int s[256];
    int idx = blockIdx.x * 256 + threadIdx.x;
    s[threadIdx.x] = (idx < n) ? cnt[idx] : 0;
    __syncthreads();
    for (int o = 128; o > 0; o >>= 1) {
        if (threadIdx.x < o) s[threadIdx.x] += s[threadIdx.x + o];
        __syncthreads();
    }
    if (threadIdx.x == 0) bsum[blockIdx.x] = s[0];
}
__global__ __launch_bounds__(256) void scan_partials(const int* __restrict__ bsum,
                                                     int* __restrict__ bsumex, int nb) {
    __shared__ int s[256];
    int t = threadIdx.x;
    int v = (t < nb) ? bsum[t] : 0;
    s[t] = v;
    __syncthreads();
    for (int o = 1; o < 256; o <<= 1) {
        int add = (t >= o) ? s[t - o] : 0;
        __syncthreads();
        s[t] += add;
        __syncthreads();
    }
    bsumex[t] = s[t] - v;
}
__global__ __launch_bounds__(256) void scan_write(const int* __restrict__ cnt,
                                                  const int* __restrict__ bsumex,
                                                  int* __restrict__ rowptr,
                                                  int* __restrict__ cursor, int n, int etot) {
    __shared__ int s[256];
    int t = threadIdx.x;
    int idx = blockIdx.x * 256 + t;
    int v = (idx < n) ? cnt[idx] : 0;
    s[t] = v;
    __syncthreads();
    for (int o = 1; o < 256; o <<= 1) {
        int add = (t >= o) ? s[t - o] : 0;
        __syncthreads();
        s[t] += add;
        __syncthreads();
    }
    if (idx < n) {
        int ex = bsumex[blockIdx.x] + s[t] - v;
        rowptr[idx] = ex;
        cursor[idx] = ex;
    }
    if (idx == 0) rowptr[n] = etot;
}
__global__ __launch_bounds__(256) void scatter_kernel(const int* __restrict__ dst,
                                                      int* __restrict__ cursor,
                                                      int* __restrict__ eids, int e) {
    int stride = gridDim.x * blockDim.x;
    for (int i = blockIdx.x * blockDim.x + threadIdx.x; i < e; i += stride) {
        int p = atomicAdd(&cursor[dst[i]], 1);
        eids[p] = i;
    }
}

// ---------------- Attention: one wave per dst node, online softmax, 2-edge ILP
// Lane l holds flattened qkv columns [4l, 4l+4): lanes 0-31 head 0, 32-63 head 1.
// Fuses head-mean + skip + residual; writes x2 in-place over `sx`.
__global__ __launch_bounds__(256) void attn_kernel(
    const u16* __restrict__ q, const u16* __restrict__ k,
    const u16* __restrict__ v, const int* __restrict__ rowptr,
    const int* __restrict__ eids, const int* __restrict__ src,
    const float* __restrict__ x, float* __restrict__ sx, int n)
{
    int wid = threadIdx.x >> 6, lane = threadIdx.x & 63;
    int i = blockIdx.x * 4 + wid;
    if (i >= n) return;
    ushort4 qu = *(const ushort4*)(q + (size_t)i * 256 + lane * 4);
    float q0 = bf2f(qu.x), q1 = bf2f(qu.y), q2 = bf2f(qu.z), q3 = bf2f(qu.w);
    int beg = rowptr[i], end = rowptr[i + 1];
    float m = -INFINITY, l = 0.f;
    float a0 = 0.f, a1 = 0.f, a2 = 0.f, a3 = 0.f;
    const float scale = 0.08838834764831845f;   // 1/sqrt(128)
    int t = beg;
    for (; t + 2 <= end; t += 2) {
        int e0 = eids[t], e1 = eids[t + 1];
        int s0 = src[e0], s1 = src[e1];
        ushort4 ku0 = *(const ushort4*)(k + (size_t)s0 * 256 + lane * 4);
        ushort4 ku1 = *(const ushort4*)(k + (size_t)s1 * 256 + lane * 4);
        ushort4 vu0 = *(const ushort4*)(v + (size_t)s0 * 256 + lane * 4);
        ushort4 vu1 = *(const ushort4*)(v + (size_t)s1 * 256 + lane * 4);
        float p0 = q0 * bf2f(ku0.x) + q1 * bf2f(ku0.y) + q2 * bf2f(ku0.z) + q3 * bf2f(ku0.w);
        float p1 = q0 * bf2f(ku1.x) + q1 * bf2f(ku1.y) + q2 * bf2f(ku1.z) + q3 * bf2f(ku1.w);
        p0 += __shfl_xor(p0, 1);  p1 += __shfl_xor(p1, 1);
        p0 += __shfl_xor(p0, 2);  p1 += __shfl_xor(p1, 2);
        p0 += __shfl_xor(p0, 4);  p1 += __shfl_xor(p1, 4);
        p0 += __shfl_xor(p0, 8);  p1 += __shfl_xor(p1, 8);
        p0 += __shfl_xor(p0, 16); p1 += __shfl_xor(p1, 16);
        float al0 = p0 * scale, al1 = p1 * scale;
        float nm = fmaxf(m, fmaxf(al0, al1));
        float sc = expf(m - nm);                 // m=-inf first iter -> 0
        float w0 = expf(al0 - nm), w1 = expf(al1 - nm);
        l = l * sc + w0 + w1;
        a0 = a0 * sc + w0 * bf2f(vu0.x) + w1 * bf2f(vu1.x);
        a1 = a1 * sc + w0 * bf2f(vu0.y) + w1 * bf2f(vu1.y);
        a2 = a2 * sc + w0 * bf2f(vu0.z) + w1 * bf2f(vu1.z);
        a3 = a3 * sc + w0 * bf2f(vu0.w) + w1 * bf2f(vu1.w);
        m = nm;
    }
    if (t < end) {
        int e0 = eids[t];
        int s0 = src[e0];
        ushort4 ku0 = *(const ushort4*)(k + (size_t)s0 * 256 + lane * 4);
        ushort4 vu0 = *(const ushort4*)(v + (size_t)s0 * 256 + lane * 4);
        float p0 = q0 * bf2f(ku0.x) + q1 * bf2f(ku0.y) + q2 * bf2f(ku0.z) + q3 * bf2f(ku0.w);
        p0 += __shfl_xor(p0, 1);
        p0 += __shfl_xor(p0, 2);
        p0 += __shfl_xor(p0, 4);
        p0 += __shfl_xor(p0, 8);
        p0 += __shfl_xor(p0, 16);
        float al0 = p0 * scale;
        float nm = fmaxf(m, al0);
        float sc = expf(m - nm);
        float w0 = expf(al0 - nm);
        l = l * sc + w0;
        a0 = a0 * sc + w0 * bf2f(vu0.x);
        a1 = a1 * sc + w0 * bf2f(vu0.y);
        a2 = a2 * sc + w0 * bf2f(vu0.z);
        a3 = a3 * sc + w0 * bf2f(vu0.w);
        m = nm;
    }
    float inv = (l > 0.f) ? (1.f / l) : 0.f;    // empty segment -> attn = 0
    a0 *= inv; a1 *= inv; a2 *= inv; a3 *= inv;
    float o0 = 0.5f * (a0 + __shfl_xor(a0, 32));  // mean over the 2 heads
    float o1 = 0.5f * (a1 + __shfl_xor(a1, 32));
    float o2 = 0.5f * (a2 + __shfl_xor(a2, 32));
    float o3 = 0.5f * (a3 + __shfl_xor(a3, 32));
    if (lane < 32) {
        size_t base = (size_t)i * 128 + lane * 4;
        float4 xv = *(const float4*)(x + base);
        float4 sk = *(const float4*)(sx + base);
        float4 r;
        r.x = xv.x + sk.x + o0;
        r.y = xv.y + sk.y + o1;
        r.z = xv.z + sk.z + o2;
        r.w = xv.w + sk.w + o3;
        *(float4*)(sx + base) = r;   // x2 in-place (read-before-write, same thread)
    }
}

extern "C" void kernel_launch(void* const* d_in, const int* in_sizes, int n_in,
                              void* d_out, int out_size, void* d_ws, size_t ws_size,
                              hipStream_t stream)
{
    const float* x    = (const float*)d_in[0];
    const int*   ei   = (const int*)d_in[1];
    const float* ln1g = (const float*)d_in[2];
    const float* ln1b = (const float*)d_in[3];
    const float* Wq   = (const float*)d_in[4];
    const float* bq   = (const float*)d_in[5];
    const float* Wk   = (const float*)d_in[6];
    const float* bk   = (const float*)d_in[7];
    const float* Wv   = (const float*)d_in[8];
    const float* bv   = (const float*)d_in[9];
    const float* Wsk  = (const float*)d_in[10];
    const float* bsk  = (const float*)d_in[11];
    const float* ln2g = (const float*)d_in[12];
    const float* ln2b = (const float*)d_in[13];
    const float* W1   = (const float*)d_in[14];
    const float* b1   = (const float*)d_in[15];
    const float* W2   = (const float*)d_in[16];
    const float* b2   = (const float*)d_in[17];

    int n = in_sizes[0] / 128;     // 50000
    int e = in_sizes[1] / 2;       // 800000
    const int* src  = ei;          // edge_index[0] (messages src -> dst)
    const int* dstp = ei + e;      // edge_index[1]

    char* w = (char*)d_ws;
    size_t off = 0;
    auto alloc = [&](size_t bytes) -> void* {
        void* p = w + off;
        off = (off + bytes + 255) & ~(size_t)255;
        return p;
    };
    u16*   y    = (u16*)alloc((size_t)n * 128 * 2);   // LN1 out; reused as h (LN2 out)
    u16*   qb   = (u16*)alloc((size_t)n * 256 * 2);   // q; reused as h1 (GELU out)
    u16*   kb   = (u16*)alloc((size_t)n * 256 * 2);
    u16*   vb   = (u16*)alloc((size_t)n * 256 * 2);
    float* sx   = (float*)alloc((size_t)n * 128 * 4); // skip, then x2 in-place
    u16*   wt   = (u16*)alloc((size_t)147456 * 2);    // transposed bf16 weights
    int* cnt    = (int*)alloc((size_t)n * 4);
    int* cursor = (int*)alloc((size_t)n * 4);
    int* rowptr = (int*)alloc(((size_t)n + 1) * 4);
    int* eids   = (int*)alloc((size_t)e * 4);
    int* bsum   = (int*)alloc(1024);
    int* bsumex = (int*)alloc(1024);

    const u16* WqT = wt;
    const u16* WkT = wt + 32768;
    const u16* WvT = wt + 65536;
    const u16* WsT = wt + 98304;
    const u16* W1T = wt + 114688;
    const u16* W2T = wt + 131072;

    int lnGrid = (n + 3) / 4;
    int nb = (n + 255) / 256;
    int gr = (n + 63) / 64;        // GEMM row blocks

    // weight prep + LN1 (independent)
    prep_weights<<<576, 256, 0, stream>>>(Wq, Wk, Wv, Wsk, W1, W2, wt);
    ln_kernel<<<lnGrid, 256, 0, stream>>>(x, ln1g, ln1b, y, n);
    // projections (MFMA)
    mfma_gemm<1><<<dim3(gr, 4), 256, 0, stream>>>(y, WqT, bq, qb, nullptr, n, 256);
    mfma_gemm<1><<<dim3(gr, 4), 256, 0, stream>>>(y, WkT, bk, kb, nullptr, n, 256);
    mfma_gemm<1><<<dim3(gr, 4), 256, 0, stream>>>(y, WvT, bv, vb, nullptr, n, 256);
    mfma_gemm<0><<<dim3(gr, 2), 256, 0, stream>>>(y, WsT, bsk, sx, nullptr, n, 128);
    // CSR by dst
    zero_kernel<<<nb, 256, 0, stream>>>(cnt, n);
    hist_kernel<<<1024, 256, 0, stream>>>(dstp, cnt, e);
    scan_block_sum<<<nb, 256, 0, stream>>>(cnt, bsum, n);
    scan_partials<<<1, 256, 0, stream>>>(bsum, bsumex, nb);
    scan_write<<<nb, 256, 0, stream>>>(cnt, bsumex, rowptr, cursor, n, e);
    scatter_kernel<<<1024, 256, 0, stream>>>(dstp, cursor, eids, e);
    // attention + head-mean + skip + residual -> sx (in place)
    attn_kernel<<<(n + 3) / 4, 256, 0, stream>>>(qb, kb, vb, rowptr, eids, src,
                                                 x, sx, n);
    // FFN (h into y buffer, h1 into q buffer)
    ln_kernel<<<lnGrid, 256, 0, stream>>>(sx, ln2g, ln2b, y, n);
    mfma_gemm<2><<<dim3(gr, 2), 256, 0, stream>>>(y, W1T, b1, qb, nullptr, n, 128);
    mfma_gemm<3><<<dim3(gr, 2), 256, 0, stream>>>(qb, W2T, b2, d_out, sx, n, 128);
}

// Round 4
// 466.968 us; speedup vs baseline: 1.7047x; 1.1149x over previous
//
#include <hip/hip_runtime.h>
#include <hip/hip_bf16.h>
#include <math.h>

// EncoderLayer_68186900791439 — graph transformer encoder layer on MI355X.
// Round 4: fused QKV+skip MFMA GEMM (M=896 -> interleaved qkv[n][768] + skip),
// scatter stores src directly (esrc), attention 4-edge unroll + fused LN2
// epilogue. Launches: prep, LN1, QKV-GEMM, CSR x6, attn(+LN2), FFN GEMM x2.

typedef unsigned short u16;
using short8 = __attribute__((ext_vector_type(8))) short;   // 8 bf16 = 4 VGPRs
using f32x4  = __attribute__((ext_vector_type(4))) float;   // 4 f32 acc

__device__ __forceinline__ float bf2f(u16 u) {
    return __uint_as_float(((unsigned int)u) << 16);
}
__device__ __forceinline__ u16 f2bf(float f) {
    __hip_bfloat16 h = __float2bfloat16(f);
    return __builtin_bit_cast(u16, h);
}

// ---------------- LayerNorm (LN1): one wave per row of 128; f32 in, bf16 out --
__global__ __launch_bounds__(256) void ln_kernel(
    const float* __restrict__ x, const float* __restrict__ g,
    const float* __restrict__ b, u16* __restrict__ y, int n)
{
    int wid = threadIdx.x >> 6, lane = threadIdx.x & 63;
    int row = blockIdx.x * 4 + wid;
    if (row >= n) return;
    size_t base = (size_t)row * 128;
    float v0 = x[base + lane];
    float v1 = x[base + 64 + lane];
    float s1 = v0 + v1, s2 = v0 * v0 + v1 * v1;
    for (int o = 1; o <= 32; o <<= 1) {
        s1 += __shfl_xor(s1, o);
        s2 += __shfl_xor(s2, o);
    }
    float mu = s1 * (1.f / 128.f);
    float var = s2 * (1.f / 128.f) - mu * mu;
    float rstd = rsqrtf(var + 1e-5f);
    y[base + lane]      = f2bf((v0 - mu) * rstd * g[lane] + b[lane]);
    y[base + 64 + lane] = f2bf((v1 - mu) * rstd * g[64 + lane] + b[64 + lane]);
}

// ------ Weight prep: W[128 x N] f32 -> Wt[N x 128] bf16 (q|k|v|skip|W1|W2),
// ------ plus concatenated f32 bias (bq|bk|bv|bskip) into biasCat[896].
__global__ __launch_bounds__(256) void prep_weights(
    const float* __restrict__ Wq, const float* __restrict__ Wk,
    const float* __restrict__ Wv, const float* __restrict__ Ws,
    const float* __restrict__ W1, const float* __restrict__ W2,
    const float* __restrict__ bq, const float* __restrict__ bk,
    const float* __restrict__ bv, const float* __restrict__ bs,
    u16* __restrict__ out, float* __restrict__ biasCat)
{
    int i = blockIdx.x * 256 + threadIdx.x;          // 0 .. 148351
    if (i < 147456) {
        const float* W; int N; int base;
        if      (i <  32768) { W = Wq; N = 256; base = 0; }
        else if (i <  65536) { W = Wk; N = 256; base = 32768; }
        else if (i <  98304) { W = Wv; N = 256; base = 65536; }
        else if (i < 114688) { W = Ws; N = 128; base = 98304; }
        else if (i < 131072) { W = W1; N = 128; base = 114688; }
        else                 { W = W2; N = 128; base = 131072; }
        int j = i - base;
        int nIdx = j >> 7, k = j & 127;
        out[i] = f2bf(W[(size_t)k * N + nIdx]);
    } else if (i < 147456 + 896) {
        int j = i - 147456;
        float v;
        if      (j < 256) v = bq[j];
        else if (j < 512) v = bk[j - 256];
        else if (j < 768) v = bv[j - 512];
        else              v = bs[j - 768];
        biasCat[j] = v;
    }
}

// ------------- MFMA GEMM: C[n x M] = A[n x 128] @ Bt^T + bias ----------------
// A bf16 row-major, Bt = B^T bf16 [M x 128] row-major. Wave tile: 32x64
// (2 row x 4 col accs of 16x16x32), block 2x2 waves = 64 rows x 128 cols.
// MODE 4: fused qkv+skip — cols<768 bf16 -> out[row*768+col], cols>=768 f32
//         -> aux[row*128+col-768].  MODE 2: exact GELU -> bf16 out (stride M).
// MODE 3: aux(f32 resid) + val -> f32 out (stride M).
template <int MODE>
__global__ __launch_bounds__(256) void mfma_gemm(
    const u16* __restrict__ A, const u16* __restrict__ Bt,
    const float* __restrict__ bias, void* __restrict__ out,
    float* __restrict__ aux, int n, int M)
{
    int wid = threadIdx.x >> 6, lane = threadIdx.x & 63;
    int wr = wid >> 1, wc = wid & 1;
    int r0 = blockIdx.x * 64 + wr * 32;
    int c0 = blockIdx.y * 128 + wc * 64;
    int lm = lane & 15, quad = lane >> 4;

    // Last row-block reads overrun n; they land in the adjacent ws buffer
    // (allocs contiguous) and only feed rows never stored (row<n guard).
    const u16* aBase = A  + (size_t)(r0 + lm) * 128 + quad * 8;
    const u16* bBase = Bt + (size_t)(c0 + lm) * 128 + quad * 8;

    f32x4 acc[2][4] = {};
#pragma unroll
    for (int kk = 0; kk < 128; kk += 32) {
        short8 a0 = *(const short8*)(aBase + kk);
        short8 a1 = *(const short8*)(aBase + 16 * 128 + kk);
#pragma unroll
        for (int j = 0; j < 4; ++j) {
            short8 bj = *(const short8*)(bBase + (size_t)j * 16 * 128 + kk);
            acc[0][j] = __builtin_amdgcn_mfma_f32_16x16x32_bf16(a0, bj, acc[0][j], 0, 0, 0);
            acc[1][j] = __builtin_amdgcn_mfma_f32_16x16x32_bf16(a1, bj, acc[1][j], 0, 0, 0);
        }
    }

#pragma unroll
    for (int j = 0; j < 4; ++j) {
        int col = c0 + j * 16 + lm;
        float bv = bias[col];
#pragma unroll
        for (int rt = 0; rt < 2; ++rt) {
#pragma unroll
            for (int i2 = 0; i2 < 4; ++i2) {
                int row = r0 + rt * 16 + quad * 4 + i2;
                if (row >= n) continue;
                float v = acc[rt][j][i2] + bv;
                if (MODE == 4) {
                    if (col < 768)
                        ((u16*)out)[(size_t)row * 768 + col] = f2bf(v);
                    else
                        aux[(size_t)row * 128 + col - 768] = v;
                } else if (MODE == 2) {
                    v = 0.5f * v * (1.f + erff(v * 0.70710678118654752f));
                    ((u16*)out)[(size_t)row * M + col] = f2bf(v);
                } else {
                    ((float*)out)[(size_t)row * M + col] = v + aux[(size_t)row * M + col];
                }
            }
        }
    }
}

// ---------------- CSR build (group edges by dst) ----------------
__global__ __launch_bounds__(256) void zero_kernel(int* __restrict__ p, int n) {
    int i = blockIdx.x * 256 + threadIdx.x;
    if (i < n) p[i] = 0;
}
__global__ __launch_bounds__(256) void hist_kernel(const int* __restrict__ dst,
                                                   int* __restrict__ cnt, int e) {
    int stride = gridDim.x * blockDim.x;
    for (int i = blockIdx.x * blockDim.x + threadIdx.x; i < e; i += stride)
        atomicAdd(&cnt[dst[i]], 1);
}
__global__ __launch_bounds__(256) void scan_block_sum(const int* __restrict__ cnt,
                                                      int* __restrict__ bsum, int n) {
    __shared__ int s[256];
    int idx = blockIdx.x * 256 + threadIdx.x;
    s[threadIdx.x] = (idx < n) ? cnt[idx] : 0;
    __syncthreads();
    for (int o = 128; o > 0; o >>= 1) {
        if (threadIdx.x < o) s[threadIdx.x] += s[threadIdx.x + o];
        __syncthreads();
    }
    if (threadIdx.x == 0) bsum[blockIdx.x] = s[0];
}
__global__ __launch_bounds__(256) void scan_partials(const int* __restrict__ bsum,
                                                     int* __restrict__ bsumex, int nb) {
    __shared__ int s[256];
    int t = threadIdx.x;
    int v = (t < nb) ? bsum[t] : 0;
    s[t] = v;
    __syncthreads();
    for (int o = 1; o < 256; o <<= 1) {
        int add = (t >= o) ? s[t - o] : 0;
        __syncthreads();
        s[t] += add;
        __syncthreads();
    }
    bsumex[t] = s[t] - v;
}
__global__ __launch_bounds__(256) void scan_write(const int* __restrict__ cnt,
                                                  const int* __restrict__ bsumex,
                                                  int* __restrict__ rowptr,
                                                  int* __restrict__ cursor, int n, int etot) {
    __shared__ int s[256];
    int t = threadIdx.x;
    int idx = blockIdx.x * 256 + t;
    int v = (idx < n) ? cnt[idx] : 0;
    s[t] = v;
    __syncthreads();
    for (int o = 1; o < 256; o <<= 1) {
        int add = (t >= o) ? s[t - o] : 0;
        __syncthreads();
        s[t] += add;
        __syncthreads();
    }
    if (idx < n) {
        int ex = bsumex[blockIdx.x] + s[t] - v;
        rowptr[idx] = ex;
        cursor[idx] = ex;
    }
    if (idx == 0) rowptr[n] = etot;
}
// stores SRC NODE IDS grouped by dst (not edge ids) — one less indirection in attn
__global__ __launch_bounds__(256) void scatter_kernel(const int* __restrict__ dst,
                                                      const int* __restrict__ src,
                                                      int* __restrict__ cursor,
                                                      int* __restrict__ esrc, int e) {
    int stride = gridDim.x * blockDim.x;
    for (int i = blockIdx.x * blockDim.x + threadIdx.x; i < e; i += stride) {
        int p = atomicAdd(&cursor[dst[i]], 1);
        esrc[p] = src[i];
    }
}

// ------------- Attention: wave per dst node, online softmax, 4-edge ILP ------
// qkv[n][768] bf16 interleaved (q|k|v). Lane l: flattened head-cols [4l,4l+4);
// lanes 0-31 head 0, 32-63 head 1. Epilogue fuses head-mean + skip + residual
// (writes sx in place) AND LayerNorm2 (writes y bf16 for the FFN).
__global__ __launch_bounds__(256) void attn_kernel(
    const u16* __restrict__ qkv, const int* __restrict__ rowptr,
    const int* __restrict__ esrc, const float* __restrict__ x,
    float* __restrict__ sx, const float* __restrict__ g2,
    const float* __restrict__ b2, u16* __restrict__ y, int n)
{
    int wid = threadIdx.x >> 6, lane = threadIdx.x & 63;
    int i = blockIdx.x * 4 + wid;
    if (i >= n) return;
    ushort4 qu = *(const ushort4*)(qkv + (size_t)i * 768 + lane * 4);
    float q0 = bf2f(qu.x), q1 = bf2f(qu.y), q2 = bf2f(qu.z), q3 = bf2f(qu.w);
    int beg = rowptr[i], end = rowptr[i + 1];
    float m = -INFINITY, l = 0.f;
    float a0 = 0.f, a1 = 0.f, a2 = 0.f, a3 = 0.f;
    const float scale = 0.08838834764831845f;   // 1/sqrt(128)
    int t = beg;
    for (; t + 4 <= end; t += 4) {
        int s0 = esrc[t], s1 = esrc[t + 1], s2 = esrc[t + 2], s3 = esrc[t + 3];
        const u16* p0b = qkv + (size_t)s0 * 768 + lane * 4;
        const u16* p1b = qkv + (size_t)s1 * 768 + lane * 4;
        const u16* p2b = qkv + (size_t)s2 * 768 + lane * 4;
        const u16* p3b = qkv + (size_t)s3 * 768 + lane * 4;
        ushort4 ku0 = *(const ushort4*)(p0b + 256);
        ushort4 ku1 = *(const ushort4*)(p1b + 256);
        ushort4 ku2 = *(const ushort4*)(p2b + 256);
        ushort4 ku3 = *(const ushort4*)(p3b + 256);
        ushort4 vu0 = *(const ushort4*)(p0b + 512);
        ushort4 vu1 = *(const ushort4*)(p1b + 512);
        ushort4 vu2 = *(const ushort4*)(p2b + 512);
        ushort4 vu3 = *(const ushort4*)(p3b + 512);
        float d0 = q0 * bf2f(ku0.x) + q1 * bf2f(ku0.y) + q2 * bf2f(ku0.z) + q3 * bf2f(ku0.w);
        float d1 = q0 * bf2f(ku1.x) + q1 * bf2f(ku1.y) + q2 * bf2f(ku1.z) + q3 * bf2f(ku1.w);
        float d2 = q0 * bf2f(ku2.x) + q1 * bf2f(ku2.y) + q2 * bf2f(ku2.z) + q3 * bf2f(ku2.w);
        float d3 = q0 * bf2f(ku3.x) + q1 * bf2f(ku3.y) + q2 * bf2f(ku3.z) + q3 * bf2f(ku3.w);
#pragma unroll
        for (int o = 1; o <= 16; o <<= 1) {
            d0 += __shfl_xor(d0, o);
            d1 += __shfl_xor(d1, o);
            d2 += __shfl_xor(d2, o);
            d3 += __shfl_xor(d3, o);
        }
        float al0 = d0 * scale, al1 = d1 * scale;
        float al2 = d2 * scale, al3 = d3 * scale;
        float nm = fmaxf(fmaxf(m, fmaxf(al0, al1)), fmaxf(al2, al3));
        float sc = expf(m - nm);                 // m=-inf first iter -> 0
        float w0 = expf(al0 - nm), w1 = expf(al1 - nm);
        float w2 = expf(al2 - nm), w3 = expf(al3 - nm);
        l = l * sc + w0 + w1 + w2 + w3;
        a0 = a0 * sc + w0 * bf2f(vu0.x) + w1 * bf2f(vu1.x) + w2 * bf2f(vu2.x) + w3 * bf2f(vu3.x);
        a1 = a1 * sc + w0 * bf2f(vu0.y) + w1 * bf2f(vu1.y) + w2 * bf2f(vu2.y) + w3 * bf2f(vu3.y);
        a2 = a2 * sc + w0 * bf2f(vu0.z) + w1 * bf2f(vu1.z) + w2 * bf2f(vu2.z) + w3 * bf2f(vu3.z);
        a3 = a3 * sc + w0 * bf2f(vu0.w) + w1 * bf2f(vu1.w) + w2 * bf2f(vu2.w) + w3 * bf2f(vu3.w);
        m = nm;
    }
    for (; t < end; ++t) {
        int s0 = esrc[t];
        const u16* p0b = qkv + (size_t)s0 * 768 + lane * 4;
        ushort4 ku0 = *(const ushort4*)(p0b + 256);
        ushort4 vu0 = *(const ushort4*)(p0b + 512);
        float d0 = q0 * bf2f(ku0.x) + q1 * bf2f(ku0.y) + q2 * bf2f(ku0.z) + q3 * bf2f(ku0.w);
#pragma unroll
        for (int o = 1; o <= 16; o <<= 1) d0 += __shfl_xor(d0, o);
        float al0 = d0 * scale;
        float nm = fmaxf(m, al0);
        float sc = expf(m - nm);
        float w0 = expf(al0 - nm);
        l = l * sc + w0;
        a0 = a0 * sc + w0 * bf2f(vu0.x);
        a1 = a1 * sc + w0 * bf2f(vu0.y);
        a2 = a2 * sc + w0 * bf2f(vu0.z);
        a3 = a3 * sc + w0 * bf2f(vu0.w);
        m = nm;
    }
    float inv = (l > 0.f) ? (1.f / l) : 0.f;    // empty segment -> attn = 0
    a0 *= inv; a1 *= inv; a2 *= inv; a3 *= inv;
    float o0 = 0.5f * (a0 + __shfl_xor(a0, 32));  // mean over the 2 heads
    float o1 = 0.5f * (a1 + __shfl_xor(a1, 32));
    float o2 = 0.5f * (a2 + __shfl_xor(a2, 32));
    float o3 = 0.5f * (a3 + __shfl_xor(a3, 32));
    if (lane < 32) {
        size_t base = (size_t)i * 128 + lane * 4;
        float4 xv = *(const float4*)(x + base);
        float4 sk = *(const float4*)(sx + base);
        float4 r;
        r.x = xv.x + sk.x + o0;
        r.y = xv.y + sk.y + o1;
        r.z = xv.z + sk.z + o2;
        r.w = xv.w + sk.w + o3;
        *(float4*)(sx + base) = r;   // x2 in-place

        // ---- fused LayerNorm2 over the row held by lanes 0..31 ----
        float s1 = r.x + r.y + r.z + r.w;
        float s2 = r.x * r.x + r.y * r.y + r.z * r.z + r.w * r.w;
#pragma unroll
        for (int o = 1; o <= 16; o <<= 1) {
            s1 += __shfl_xor(s1, o);
            s2 += __shfl_xor(s2, o);
        }
        float mu = s1 * (1.f / 128.f);
        float var = s2 * (1.f / 128.f) - mu * mu;
        float rstd = rsqrtf(var + 1e-5f);
        float4 gv = *(const float4*)(g2 + lane * 4);
        float4 bv = *(const float4*)(b2 + lane * 4);
        ushort4 o4;
        o4.x = f2bf((r.x - mu) * rstd * gv.x + bv.x);
        o4.y = f2bf((r.y - mu) * rstd * gv.y + bv.y);
        o4.z = f2bf((r.z - mu) * rstd * gv.z + bv.z);
        o4.w = f2bf((r.w - mu) * rstd * gv.w + bv.w);
        *(ushort4*)(y + base) = o4;
    }
}

extern "C" void kernel_launch(void* const* d_in, const int* in_sizes, int n_in,
                              void* d_out, int out_size, void* d_ws, size_t ws_size,
                              hipStream_t stream)
{
    const float* x    = (const float*)d_in[0];
    const int*   ei   = (const int*)d_in[1];
    const float* ln1g = (const float*)d_in[2];
    const float* ln1b = (const float*)d_in[3];
    const float* Wq   = (const float*)d_in[4];
    const float* bq   = (const float*)d_in[5];
    const float* Wk   = (const float*)d_in[6];
    const float* bk   = (const float*)d_in[7];
    const float* Wv   = (const float*)d_in[8];
    const float* bv   = (const float*)d_in[9];
    const float* Wsk  = (const float*)d_in[10];
    const float* bsk  = (const float*)d_in[11];
    const float* ln2g = (const float*)d_in[12];
    const float* ln2b = (const float*)d_in[13];
    const float* W1   = (const float*)d_in[14];
    const float* b1   = (const float*)d_in[15];
    const float* W2   = (const float*)d_in[16];
    const float* b2   = (const float*)d_in[17];

    int n = in_sizes[0] / 128;     // 50000
    int e = in_sizes[1] / 2;       // 800000
    const int* src  = ei;          // edge_index[0] (messages src -> dst)
    const int* dstp = ei + e;      // edge_index[1]

    char* w = (char*)d_ws;
    size_t off = 0;
    auto alloc = [&](size_t bytes) -> void* {
        void* p = w + off;
        off = (off + bytes + 255) & ~(size_t)255;
        return p;
    };
    u16*   y    = (u16*)alloc((size_t)n * 128 * 2);   // LN1 out, then LN2 out
    u16*   qkv  = (u16*)alloc((size_t)n * 768 * 2);   // q|k|v interleaved; head reused as h1
    float* sx   = (float*)alloc((size_t)n * 128 * 4); // skip, then x2 in-place
    u16*   wt   = (u16*)alloc((size_t)147456 * 2);    // transposed bf16 weights
    float* bc   = (float*)alloc(896 * 4);             // concatenated qkv+skip bias
    int* cnt    = (int*)alloc((size_t)n * 4);
    int* cursor = (int*)alloc((size_t)n * 4);
    int* rowptr = (int*)alloc(((size_t)n + 1) * 4);
    int* esrc   = (int*)alloc((size_t)e * 4);
    int* bsum   = (int*)alloc(1024);
    int* bsumex = (int*)alloc(1024);

    const u16* W1T = wt + 114688;
    const u16* W2T = wt + 131072;
    u16* h1 = qkv;                 // reuse qkv region for GELU output (after attn)

    int lnGrid = (n + 3) / 4;
    int nb = (n + 255) / 256;
    int gr = (n + 63) / 64;        // GEMM row blocks

    prep_weights<<<580, 256, 0, stream>>>(Wq, Wk, Wv, Wsk, W1, W2,
                                          bq, bk, bv, bsk, wt, bc);
    ln_kernel<<<lnGrid, 256, 0, stream>>>(x, ln1g, ln1b, y, n);
    // fused q|k|v|skip projection
    mfma_gemm<4><<<dim3(gr, 7), 256, 0, stream>>>(y, wt, bc, qkv, sx, n, 896);
    // CSR by dst
    zero_kernel<<<nb, 256, 0, stream>>>(cnt, n);
    hist_kernel<<<1024, 256, 0, stream>>>(dstp, cnt, e);
    scan_block_sum<<<nb, 256, 0, stream>>>(cnt, bsum, n);
    scan_partials<<<1, 256, 0, stream>>>(bsum, bsumex, nb);
    scan_write<<<nb, 256, 0, stream>>>(cnt, bsumex, rowptr, cursor, n, e);
    scatter_kernel<<<1024, 256, 0, stream>>>(dstp, src, cursor, esrc, e);
    // attention + head-mean + skip + residual + LN2 (writes sx=x2 and y=LN2 out)
    attn_kernel<<<(n + 3) / 4, 256, 0, stream>>>(qkv, rowptr, esrc, x, sx,
                                                 ln2g, ln2b, y, n);
    // FFN
    mfma_gemm<2><<<dim3(gr, 1), 256, 0, stream>>>(y, W1T, b1, h1, nullptr, n, 128);
    mfma_gemm<3><<<dim3(gr, 1), 256, 0, stream>>>(h1, W2T, b2, d_out, sx, n, 128);
}